// Round 1
// baseline (336.890 us; speedup 1.0000x reference)
//
#include <hip/hip_runtime.h>
#include <hip/hip_bf16.h>
#include <stdint.h>

// GPT-2 prefill attention: B=2, S=2048, D=1024, H=16, hd=64.
// Pipeline: cvt/transpose prepass -> QKV GEMM (bf16 MFMA) -> flash attn -> proj GEMM.
// All bf16 compute via mfma_f32_16x16x32_bf16; fp32 accumulate.

typedef __attribute__((ext_vector_type(4))) float f32x4;
typedef __attribute__((ext_vector_type(8))) short s16x8;
typedef __attribute__((ext_vector_type(4))) short s16x4;
typedef unsigned short u16;

#define LOG2E 1.4426950408889634f

__device__ __forceinline__ u16 f2bf(float f) {
  unsigned int x = __builtin_bit_cast(unsigned int, f);
  x += 0x7fffu + ((x >> 16) & 1u);   // RNE
  return (u16)(x >> 16);
}

__device__ __forceinline__ void gload_lds16(const u16* g, u16* lds) {
  __builtin_amdgcn_global_load_lds(
      (const __attribute__((address_space(1))) unsigned int*)g,
      (__attribute__((address_space(3))) unsigned int*)lds, 16, 0, 0);
}

// ---------------- prepass kernels ----------------

__global__ __launch_bounds__(256) void cvt_f32_bf16(const float* __restrict__ x,
                                                    u16* __restrict__ y, int n4) {
  int i = blockIdx.x * 256 + threadIdx.x;
  if (i < n4) {
    f32x4 v = *(const f32x4*)&x[(size_t)i * 4];
    s16x4 o;
    o[0] = (short)f2bf(v[0]); o[1] = (short)f2bf(v[1]);
    o[2] = (short)f2bf(v[2]); o[3] = (short)f2bf(v[3]);
    *(s16x4*)&y[(size_t)i * 4] = o;
  }
}

// W[K][N] f32 -> WT[N][K] bf16
__global__ __launch_bounds__(256) void transpose_w_bf16(const float* __restrict__ W,
                                                        u16* __restrict__ WT,
                                                        int K, int N) {
  __shared__ float tile[32][33];
  const int n0 = blockIdx.x * 32, k0 = blockIdx.y * 32;
  const int tx = threadIdx.x & 31, ty = threadIdx.x >> 5;  // ty 0..7
#pragma unroll
  for (int i = 0; i < 32; i += 8)
    tile[ty + i][tx] = W[(size_t)(k0 + ty + i) * N + (n0 + tx)];
  __syncthreads();
#pragma unroll
  for (int i = 0; i < 32; i += 8)
    WT[(size_t)(n0 + ty + i) * K + (k0 + tx)] = f2bf(tile[tx][ty + i]);
}

// ---------------- GEMM: C[M][N] = A[M][K] * BT[N][K]^T + bias ----------------
// MODE 0: QKV epilogue (scatter q/k/v), MODE 1: plain fp32 out.
// grid (N/128, M/128), 256 threads, 4 waves (2x2), wave tile 64x64.

template <int MODE>
__global__ __launch_bounds__(256) void gemm_bt(
    const u16* __restrict__ A, const u16* __restrict__ BT,
    const float* __restrict__ bias, float* __restrict__ outF,
    u16* __restrict__ q_ws, u16* __restrict__ k_ws, u16* __restrict__ vT_ws,
    int M, int N, int K) {
  __shared__ u16 As[128 * 32];
  __shared__ u16 Bs[128 * 32];
  const int m0 = blockIdx.y * 128, n0 = blockIdx.x * 128;
  const int tid = threadIdx.x;
  const int wid = tid >> 6, lane = tid & 63;
  const int c = lane & 15, hi = lane >> 4;
  const int wm = wid >> 1, wn = wid & 1;
  const int srow = lane >> 2;       // 0..15
  const int skp = (lane & 3) * 8;   // 0,8,16,24

  f32x4 acc[4][4] = {};

  for (int k0 = 0; k0 < K; k0 += 32) {
#pragma unroll
    for (int t = 0; t < 2; t++) {
      const int rowl = wid * 32 + t * 16;
      gload_lds16(&A[(size_t)(m0 + rowl + srow) * K + k0 + skp], &As[rowl * 32]);
      gload_lds16(&BT[(size_t)(n0 + rowl + srow) * K + k0 + skp], &Bs[rowl * 32]);
    }
    __syncthreads();
    s16x8 af[4], bfr[4];
#pragma unroll
    for (int i = 0; i < 4; i++)
      af[i] = *(const s16x8*)&As[(wm * 64 + i * 16 + c) * 32 + hi * 8];
#pragma unroll
    for (int i = 0; i < 4; i++)
      bfr[i] = *(const s16x8*)&Bs[(wn * 64 + i * 16 + c) * 32 + hi * 8];
#pragma unroll
    for (int i = 0; i < 4; i++)
#pragma unroll
      for (int j = 0; j < 4; j++)
        acc[i][j] = __builtin_amdgcn_mfma_f32_16x16x32_bf16(af[i], bfr[j], acc[i][j], 0, 0, 0);
    __syncthreads();
  }

#pragma unroll
  for (int i = 0; i < 4; i++) {
#pragma unroll
    for (int j = 0; j < 4; j++) {
      const int col = n0 + wn * 64 + j * 16 + c;
      const int rb = m0 + wm * 64 + i * 16 + hi * 4;
      const float bv = bias[col];
      if (MODE == 1) {
#pragma unroll
        for (int u = 0; u < 4; u++)
          outF[(size_t)(rb + u) * N + col] = acc[i][j][u] + bv;
      } else {
        const int which = col >> 10;          // 0=q 1=k 2=v
        const int h = (col >> 6) & 15, d = col & 63;
#pragma unroll
        for (int u = 0; u < 4; u++) {
          const int r = rb + u;
          const int b = r >> 11, s = r & 2047;
          const size_t idx = (size_t)(b * 16 + h) * 131072u + (size_t)s * 64 + d;
          const float v = acc[i][j][u] + bv;
          if (which == 0) {
            q_ws[idx] = f2bf(v * 0.125f);     // fold 1/sqrt(hd)
          } else if (which == 1) {
            outF[4194304u + idx] = v;
            k_ws[idx] = f2bf(v);
          } else {
            outF[8388608u + idx] = v;
            vT_ws[(size_t)(b * 16 + h) * 131072u + (size_t)d * 2048 + s] = f2bf(v);
          }
        }
      }
    }
  }
}

// ---------------- fused causal attention ----------------
// grid = 32 (b*h) * 32 (q tiles of 64). 4 waves x 16 q-rows.
// K/V fragments straight from global (L2-resident per head). P via swizzled LDS.

__global__ __launch_bounds__(256) void attn_fused(
    const u16* __restrict__ q_ws, const u16* __restrict__ k_ws,
    const u16* __restrict__ vT_ws, const float* __restrict__ bias,
    u16* __restrict__ ctx) {
  __shared__ u16 P_lds[4 * 16 * 64];  // 2KB per wave
  const int bh = blockIdx.x >> 5;
  const int qblk = 31 - (blockIdx.x & 31);   // long blocks first
  const int wid = threadIdx.x >> 6, lane = threadIdx.x & 63;
  const int c = lane & 15, hi = lane >> 4;
  const int qrow0 = qblk * 64 + wid * 16;

  const u16* qh = q_ws + (size_t)bh * 131072u;
  const u16* kh = k_ws + (size_t)bh * 131072u;
  const u16* vh = vT_ws + (size_t)bh * 131072u;

  const s16x8 qf0 = *(const s16x8*)&qh[(size_t)(qrow0 + c) * 64 + hi * 8];
  const s16x8 qf1 = *(const s16x8*)&qh[(size_t)(qrow0 + c) * 64 + 32 + hi * 8];

  f32x4 o[4] = {};
  float mrow[4] = {-1e30f, -1e30f, -1e30f, -1e30f};
  float lrow[4] = {0.f, 0.f, 0.f, 0.f};

  u16* pw = &P_lds[wid * 1024];
  const int nkt = qblk + 1;
  for (int kt = 0; kt < nkt; ++kt) {
    const int n0 = kt * 64;
    f32x4 sfr[4];
#pragma unroll
    for (int nf = 0; nf < 4; nf++) {
      const u16* kp = &kh[(size_t)(n0 + nf * 16 + c) * 64];
      const s16x8 kf0 = *(const s16x8*)&kp[hi * 8];
      const s16x8 kf1 = *(const s16x8*)&kp[32 + hi * 8];
      f32x4 a = {};
      a = __builtin_amdgcn_mfma_f32_16x16x32_bf16(qf0, kf0, a, 0, 0, 0);
      a = __builtin_amdgcn_mfma_f32_16x16x32_bf16(qf1, kf1, a, 0, 0, 0);
      sfr[nf] = a;
    }
    const bool need_mask = (n0 + 63 > qrow0);
#pragma unroll
    for (int nf = 0; nf < 4; nf++) {
      const int kg = n0 + nf * 16 + c;
#pragma unroll
      for (int u = 0; u < 4; u++) {
        const int qg = qrow0 + hi * 4 + u;
        float s = sfr[nf][u] + bias[(size_t)qg * 2048 + kg];
        if (need_mask && kg > qg) s = -1e30f;
        sfr[nf][u] = s;
      }
    }
    // online softmax (row reduce over low-4 lane bits)
    float al[4];
#pragma unroll
    for (int u = 0; u < 4; u++) {
      float t = fmaxf(fmaxf(sfr[0][u], sfr[1][u]), fmaxf(sfr[2][u], sfr[3][u]));
      t = fmaxf(t, __shfl_xor(t, 1));
      t = fmaxf(t, __shfl_xor(t, 2));
      t = fmaxf(t, __shfl_xor(t, 4));
      t = fmaxf(t, __shfl_xor(t, 8));
      const float nm = fmaxf(mrow[u], t);
      al[u] = exp2f((mrow[u] - nm) * LOG2E);
      mrow[u] = nm;
    }
    float rs[4] = {0.f, 0.f, 0.f, 0.f};
#pragma unroll
    for (int nf = 0; nf < 4; nf++)
#pragma unroll
      for (int u = 0; u < 4; u++) {
        const float p = exp2f((sfr[nf][u] - mrow[u]) * LOG2E);
        sfr[nf][u] = p;
        rs[u] += p;
      }
#pragma unroll
    for (int u = 0; u < 4; u++) {
      float t = rs[u];
      t += __shfl_xor(t, 1);
      t += __shfl_xor(t, 2);
      t += __shfl_xor(t, 4);
      t += __shfl_xor(t, 8);
      lrow[u] = lrow[u] * al[u] + t;
    }
#pragma unroll
    for (int d0 = 0; d0 < 4; d0++) {
      f32x4 t = o[d0];
      t[0] *= al[0]; t[1] *= al[1]; t[2] *= al[2]; t[3] *= al[3];
      o[d0] = t;
    }
    // P (D-layout) -> LDS, XOR-swizzled: elem(r,k) at r*64 + ((k>>3)^(r&7))*8 + (k&7)
#pragma unroll
    for (int nf = 0; nf < 4; nf++) {
      const int colb = nf * 16 + c;
      const int slot = colb >> 3;
#pragma unroll
      for (int u = 0; u < 4; u++) {
        const int r = hi * 4 + u;
        pw[r * 64 + (((slot ^ (r & 7)) << 3) | (colb & 7))] = f2bf(sfr[nf][u]);
      }
    }
    // PV: A-frag from LDS, V fragment from global (vT layout [d][s])
#pragma unroll
    for (int ks = 0; ks < 2; ks++) {
      const int rslot = ks * 4 + hi;
      const s16x8 pf = *(const s16x8*)&pw[c * 64 + ((rslot ^ (c & 7)) << 3)];
#pragma unroll
      for (int d0 = 0; d0 < 4; d0++) {
        const s16x8 vf = *(const s16x8*)&vh[(size_t)(d0 * 16 + c) * 2048 + n0 + ks * 32 + hi * 8];
        o[d0] = __builtin_amdgcn_mfma_f32_16x16x32_bf16(pf, vf, o[d0], 0, 0, 0);
      }
    }
  }

  const int b = bh >> 4, h = bh & 15;
#pragma unroll
  for (int u = 0; u < 4; u++) {
    const float inv = 1.0f / lrow[u];
    const int tok = b * 2048 + qrow0 + hi * 4 + u;
#pragma unroll
    for (int d0 = 0; d0 < 4; d0++)
      ctx[(size_t)tok * 1024 + h * 64 + d0 * 16 + c] = f2bf(o[d0][u] * inv);
  }
}

// ---------------- launch ----------------

extern "C" void kernel_launch(void* const* d_in, const int* in_sizes, int n_in,
                              void* d_out, int out_size, void* d_ws, size_t ws_size,
                              hipStream_t stream) {
  const float* hs        = (const float*)d_in[0];  // [2,2048,1024]
  const float* c_attn_w  = (const float*)d_in[1];  // [1024,3072]
  const float* c_attn_b  = (const float*)d_in[2];  // [3072]
  const float* attn_bias = (const float*)d_in[3];  // [2048,2048]
  const float* c_proj_w  = (const float*)d_in[4];  // [1024,1024]
  const float* c_proj_b  = (const float*)d_in[5];  // [1024]
  float* out = (float*)d_out;  // out(4M) | k(4M) | v(4M)

  uint8_t* ws = (uint8_t*)d_ws;
  u16* hsb    = (u16*)(ws + 0);           // 8MB  [4096][1024] bf16
  u16* wqkvT  = (u16*)(ws + 8388608u);    // 6MB  [3072][1024] bf16
  u16* wprojT = (u16*)(ws + 14680064u);   // 2MB  [1024][1024] bf16
  u16* q_ws   = (u16*)(ws + 16777216u);   // 8MB  [B,H,S,hd] bf16 (q/8)
  u16* k_ws   = (u16*)(ws + 25165824u);   // 8MB  [B,H,S,hd] bf16
  u16* vT_ws  = (u16*)(ws + 33554432u);   // 8MB  [B,H,hd,S] bf16
  u16* ctx    = (u16*)(ws + 41943040u);   // 8MB  [4096][1024] bf16

  cvt_f32_bf16<<<4096, 256, 0, stream>>>(hs, hsb, 1048576);
  transpose_w_bf16<<<dim3(96, 32), 256, 0, stream>>>(c_attn_w, wqkvT, 1024, 3072);
  transpose_w_bf16<<<dim3(32, 32), 256, 0, stream>>>(c_proj_w, wprojT, 1024, 1024);

  gemm_bt<0><<<dim3(24, 32), 256, 0, stream>>>(hsb, wqkvT, c_attn_b, out,
                                               q_ws, k_ws, vT_ws, 4096, 3072, 1024);

  attn_fused<<<dim3(1024), 256, 0, stream>>>(q_ws, k_ws, vT_ws, attn_bias, ctx);

  gemm_bt<1><<<dim3(8, 32), 256, 0, stream>>>(ctx, wprojT, c_proj_b, out,
                                              (u16*)nullptr, (u16*)nullptr, (u16*)nullptr,
                                              4096, 1024, 1024);
}

// Round 2
// 179.345 us; speedup vs baseline: 1.8784x; 1.8784x over previous
//
#include <hip/hip_runtime.h>
#include <hip/hip_bf16.h>
#include <stdint.h>

// GPT-2 prefill attention: B=2, S=2048, D=1024, H=16, hd=64.
// Pipeline: cvt/transpose prepass -> QKV GEMM (bf16 MFMA) -> flash attn -> proj GEMM.

typedef __attribute__((ext_vector_type(4))) float f32x4;
typedef __attribute__((ext_vector_type(8))) short s16x8;
typedef __attribute__((ext_vector_type(4))) short s16x4;
typedef unsigned short u16;

#define LOG2E 1.4426950408889634f

__device__ __forceinline__ u16 f2bf(float f) {
  unsigned int x = __builtin_bit_cast(unsigned int, f);
  x += 0x7fffu + ((x >> 16) & 1u);   // RNE
  return (u16)(x >> 16);
}
__device__ __forceinline__ float bf2f(u16 h) {
  unsigned int x = ((unsigned int)h) << 16;
  return __builtin_bit_cast(float, x);
}

__device__ __forceinline__ void gload_lds16(const u16* g, u16* lds) {
  __builtin_amdgcn_global_load_lds(
      (const __attribute__((address_space(1))) unsigned int*)g,
      (__attribute__((address_space(3))) unsigned int*)lds, 16, 0, 0);
}

// ---------------- prepass kernels ----------------

__global__ __launch_bounds__(256) void cvt_f32_bf16(const float* __restrict__ x,
                                                    u16* __restrict__ y, int n4) {
  int i = blockIdx.x * 256 + threadIdx.x;
  if (i < n4) {
    f32x4 v = *(const f32x4*)&x[(size_t)i * 4];
    s16x4 o;
    o[0] = (short)f2bf(v[0]); o[1] = (short)f2bf(v[1]);
    o[2] = (short)f2bf(v[2]); o[3] = (short)f2bf(v[3]);
    *(s16x4*)&y[(size_t)i * 4] = o;
  }
}

// W[K][N] f32 -> WT[N][K] bf16
__global__ __launch_bounds__(256) void transpose_w_bf16(const float* __restrict__ W,
                                                        u16* __restrict__ WT,
                                                        int K, int N) {
  __shared__ float tile[32][33];
  const int n0 = blockIdx.x * 32, k0 = blockIdx.y * 32;
  const int tx = threadIdx.x & 31, ty = threadIdx.x >> 5;  // ty 0..7
#pragma unroll
  for (int i = 0; i < 32; i += 8)
    tile[ty + i][tx] = W[(size_t)(k0 + ty + i) * N + (n0 + tx)];
  __syncthreads();
#pragma unroll
  for (int i = 0; i < 32; i += 8)
    WT[(size_t)(n0 + ty + i) * K + (k0 + tx)] = f2bf(tile[tx][ty + i]);
}

// ---------------- GEMM: C[M][N] = A[M][K] * BT[N][K]^T + bias ----------------

template <int MODE>
__global__ __launch_bounds__(256) void gemm_bt(
    const u16* __restrict__ A, const u16* __restrict__ BT,
    const float* __restrict__ bias, float* __restrict__ outF,
    u16* __restrict__ q_ws, u16* __restrict__ k_ws, u16* __restrict__ vT_ws,
    int M, int N, int K) {
  __shared__ u16 As[128 * 32];
  __shared__ u16 Bs[128 * 32];
  const int m0 = blockIdx.y * 128, n0 = blockIdx.x * 128;
  const int tid = threadIdx.x;
  const int wid = tid >> 6, lane = tid & 63;
  const int c = lane & 15, hi = lane >> 4;
  const int wm = wid >> 1, wn = wid & 1;
  const int srow = lane >> 2;       // 0..15
  const int skp = (lane & 3) * 8;   // 0,8,16,24

  f32x4 acc[4][4] = {};

  for (int k0 = 0; k0 < K; k0 += 32) {
#pragma unroll
    for (int t = 0; t < 2; t++) {
      const int rowl = wid * 32 + t * 16;
      gload_lds16(&A[(size_t)(m0 + rowl + srow) * K + k0 + skp], &As[rowl * 32]);
      gload_lds16(&BT[(size_t)(n0 + rowl + srow) * K + k0 + skp], &Bs[rowl * 32]);
    }
    __syncthreads();
    s16x8 af[4], bfr[4];
#pragma unroll
    for (int i = 0; i < 4; i++)
      af[i] = *(const s16x8*)&As[(wm * 64 + i * 16 + c) * 32 + hi * 8];
#pragma unroll
    for (int i = 0; i < 4; i++)
      bfr[i] = *(const s16x8*)&Bs[(wn * 64 + i * 16 + c) * 32 + hi * 8];
#pragma unroll
    for (int i = 0; i < 4; i++)
#pragma unroll
      for (int j = 0; j < 4; j++)
        acc[i][j] = __builtin_amdgcn_mfma_f32_16x16x32_bf16(af[i], bfr[j], acc[i][j], 0, 0, 0);
    __syncthreads();
  }

#pragma unroll
  for (int i = 0; i < 4; i++) {
#pragma unroll
    for (int j = 0; j < 4; j++) {
      const int col = n0 + wn * 64 + j * 16 + c;
      const int rb = m0 + wm * 64 + i * 16 + hi * 4;
      const float bv = bias[col];
      if (MODE == 1) {
#pragma unroll
        for (int u = 0; u < 4; u++)
          outF[(size_t)(rb + u) * N + col] = acc[i][j][u] + bv;
      } else {
        const int which = col >> 10;          // 0=q 1=k 2=v
        const int h = (col >> 6) & 15, d = col & 63;
#pragma unroll
        for (int u = 0; u < 4; u++) {
          const int r = rb + u;
          const int b = r >> 11, s = r & 2047;
          const size_t idx = (size_t)(b * 16 + h) * 131072u + (size_t)s * 64 + d;
          const float v = acc[i][j][u] + bv;
          if (which == 0) {
            q_ws[idx] = f2bf(v * 0.125f);     // fold 1/sqrt(hd)
          } else if (which == 1) {
            outF[4194304u + idx] = v;
            k_ws[idx] = f2bf(v);
          } else {
            outF[8388608u + idx] = v;
            vT_ws[(size_t)(b * 16 + h) * 131072u + (size_t)d * 2048 + s] = f2bf(v);
          }
        }
      }
    }
  }
}

// ---------------- fused causal attention ----------------
// 1024 blocks, 4 waves. Balanced (bh,qblk) remap: same-CU blocks share a head,
// per-XCD K/V working set ~2MB (L2-fit), per-CU tile-unit sum constant (66).
// K/V staged in LDS (double-buffered, XOR-swizzled via pre-swizzled global src).

__global__ __launch_bounds__(256, 4) void attn_fused(
    const u16* __restrict__ q_ws, const u16* __restrict__ k_ws,
    const u16* __restrict__ vT_ws, const u16* __restrict__ biasb,
    u16* __restrict__ ctx) {
  __shared__ u16 Ks[2][64 * 64];
  __shared__ u16 Vs[2][64 * 64];
  __shared__ u16 P_lds[4 * 16 * 64];

  const int id = blockIdx.x;
  const int bh = (id & 7) * 4 + ((id >> 3) & 3);
  const int j = id >> 5, j0 = j & 7, sg = j >> 3;
  const int qblk = (sg == 0) ? j0 : (sg == 1) ? (15 - j0)
                 : (sg == 2) ? (16 + j0) : (31 - j0);

  const int wid = threadIdx.x >> 6, lane = threadIdx.x & 63;
  const int c = lane & 15, hi = lane >> 4;
  const int qrow0 = qblk * 64 + wid * 16;

  const u16* qh = q_ws + (size_t)bh * 131072u;
  const u16* kh = k_ws + (size_t)bh * 131072u;
  const u16* vh = vT_ws + (size_t)bh * 131072u;

  const s16x8 qf0 = *(const s16x8*)&qh[(size_t)(qrow0 + c) * 64 + hi * 8];
  const s16x8 qf1 = *(const s16x8*)&qh[(size_t)(qrow0 + c) * 64 + 32 + hi * 8];

  // staging decomposition: lane -> (row-in-8, chunk), source pre-swizzled
  const int sl_r = lane >> 3;   // 0..7
  const int sl_c = lane & 7;    // 16B chunk 0..7

  f32x4 o[4] = {};
  float mrow[4] = {-1e30f, -1e30f, -1e30f, -1e30f};
  float lrow[4] = {0.f, 0.f, 0.f, 0.f};
  u16* pw = &P_lds[wid * 1024];

  const int nkt = qblk + 1;

  // stage(buf, n0): this wave stages K rows / V rows [wid*16, wid*16+16)
#define STAGE(BUF, N0)                                                        \
  {                                                                           \
    _Pragma("unroll")                                                         \
    for (int t = 0; t < 2; t++) {                                             \
      const int rb = wid * 16 + t * 8;                                        \
      const int r = rb + sl_r;                                                \
      gload_lds16(&kh[(size_t)((N0) + r) * 64 + ((sl_c ^ (r & 7)) * 8)],      \
                  &Ks[BUF][rb * 64]);                                         \
      gload_lds16(&vh[(size_t)r * 2048 + (N0) + ((sl_c ^ (r & 7)) * 8)],      \
                  &Vs[BUF][rb * 64]);                                         \
    }                                                                         \
  }

  STAGE(0, 0);
  __syncthreads();

  int buf = 0;
  const int sw0 = (hi ^ (c & 7)) * 8;
  const int sw1 = ((4 + hi) ^ (c & 7)) * 8;

  for (int kt = 0; kt < nkt; ++kt) {
    const int n0 = kt * 64;
    if (kt + 1 < nkt) {
      if (buf) { STAGE(0, n0 + 64); } else { STAGE(1, n0 + 64); }
    }

    // bias for current tile (bf16, L3-served)
    float bv[4][4];
#pragma unroll
    for (int nf = 0; nf < 4; nf++)
#pragma unroll
      for (int u = 0; u < 4; u++)
        bv[nf][u] = bf2f(biasb[(size_t)(qrow0 + hi * 4 + u) * 2048 + (n0 + nf * 16 + c)]);

    // QK^T from LDS
    f32x4 sfr[4];
#pragma unroll
    for (int nf = 0; nf < 4; nf++) {
      const int row = nf * 16 + c;
      const s16x8 kf0 = *(const s16x8*)&Ks[buf][row * 64 + sw0];
      const s16x8 kf1 = *(const s16x8*)&Ks[buf][row * 64 + sw1];
      f32x4 a = {};
      a = __builtin_amdgcn_mfma_f32_16x16x32_bf16(qf0, kf0, a, 0, 0, 0);
      a = __builtin_amdgcn_mfma_f32_16x16x32_bf16(qf1, kf1, a, 0, 0, 0);
      sfr[nf] = a;
    }

    const bool need_mask = (n0 + 63 > qrow0);
#pragma unroll
    for (int nf = 0; nf < 4; nf++) {
      const int kg = n0 + nf * 16 + c;
#pragma unroll
      for (int u = 0; u < 4; u++) {
        const int qg = qrow0 + hi * 4 + u;
        float s = sfr[nf][u] + bv[nf][u];
        if (need_mask && kg > qg) s = -1e30f;
        sfr[nf][u] = s;
      }
    }

    // online softmax
    float al[4];
#pragma unroll
    for (int u = 0; u < 4; u++) {
      float t = fmaxf(fmaxf(sfr[0][u], sfr[1][u]), fmaxf(sfr[2][u], sfr[3][u]));
      t = fmaxf(t, __shfl_xor(t, 1));
      t = fmaxf(t, __shfl_xor(t, 2));
      t = fmaxf(t, __shfl_xor(t, 4));
      t = fmaxf(t, __shfl_xor(t, 8));
      const float nm = fmaxf(mrow[u], t);
      al[u] = exp2f((mrow[u] - nm) * LOG2E);
      mrow[u] = nm;
    }
    float rs[4] = {0.f, 0.f, 0.f, 0.f};
#pragma unroll
    for (int nf = 0; nf < 4; nf++)
#pragma unroll
      for (int u = 0; u < 4; u++) {
        const float p = exp2f((sfr[nf][u] - mrow[u]) * LOG2E);
        sfr[nf][u] = p;
        rs[u] += p;
      }
#pragma unroll
    for (int u = 0; u < 4; u++) {
      float t = rs[u];
      t += __shfl_xor(t, 1);
      t += __shfl_xor(t, 2);
      t += __shfl_xor(t, 4);
      t += __shfl_xor(t, 8);
      lrow[u] = lrow[u] * al[u] + t;
    }
#pragma unroll
    for (int d0 = 0; d0 < 4; d0++) {
      f32x4 t = o[d0];
      t[0] *= al[0]; t[1] *= al[1]; t[2] *= al[2]; t[3] *= al[3];
      o[d0] = t;
    }

    // P (D-layout) -> LDS, XOR-swizzled
#pragma unroll
    for (int nf = 0; nf < 4; nf++) {
      const int colb = nf * 16 + c;
      const int slot = colb >> 3;
#pragma unroll
      for (int u = 0; u < 4; u++) {
        const int r = hi * 4 + u;
        pw[r * 64 + (((slot ^ (r & 7)) << 3) | (colb & 7))] = f2bf(sfr[nf][u]);
      }
    }

    // PV: P from LDS (A-frag), V from LDS (swizzled)
#pragma unroll
    for (int ks = 0; ks < 2; ks++) {
      const int rslot = ks * 4 + hi;
      const s16x8 pf = *(const s16x8*)&pw[c * 64 + ((rslot ^ (c & 7)) << 3)];
      const int sw = ks ? sw1 : sw0;
#pragma unroll
      for (int d0 = 0; d0 < 4; d0++) {
        const s16x8 vf = *(const s16x8*)&Vs[buf][(d0 * 16 + c) * 64 + sw];
        o[d0] = __builtin_amdgcn_mfma_f32_16x16x32_bf16(pf, vf, o[d0], 0, 0, 0);
      }
    }

    __syncthreads();
    buf ^= 1;
  }
#undef STAGE

  const int b = bh >> 4, h = bh & 15;
#pragma unroll
  for (int u = 0; u < 4; u++) {
    const float inv = 1.0f / lrow[u];
    const int tok = b * 2048 + qrow0 + hi * 4 + u;
#pragma unroll
    for (int d0 = 0; d0 < 4; d0++)
      ctx[(size_t)tok * 1024 + h * 64 + d0 * 16 + c] = f2bf(o[d0][u] * inv);
  }
}

// ---------------- launch ----------------

extern "C" void kernel_launch(void* const* d_in, const int* in_sizes, int n_in,
                              void* d_out, int out_size, void* d_ws, size_t ws_size,
                              hipStream_t stream) {
  const float* hs        = (const float*)d_in[0];  // [2,2048,1024]
  const float* c_attn_w  = (const float*)d_in[1];  // [1024,3072]
  const float* c_attn_b  = (const float*)d_in[2];  // [3072]
  const float* attn_bias = (const float*)d_in[3];  // [2048,2048]
  const float* c_proj_w  = (const float*)d_in[4];  // [1024,1024]
  const float* c_proj_b  = (const float*)d_in[5];  // [1024]
  float* out = (float*)d_out;  // out(4M) | k(4M) | v(4M)

  uint8_t* ws = (uint8_t*)d_ws;
  u16* hsb    = (u16*)(ws + 0);           // 8MB  [4096][1024] bf16 (later reused for bias bf16)
  u16* wqkvT  = (u16*)(ws + 8388608u);    // 6MB  [3072][1024] bf16
  u16* wprojT = (u16*)(ws + 14680064u);   // 2MB  [1024][1024] bf16
  u16* q_ws   = (u16*)(ws + 16777216u);   // 8MB  [B,H,S,hd] bf16 (q/8)
  u16* k_ws   = (u16*)(ws + 25165824u);   // 8MB  [B,H,S,hd] bf16
  u16* vT_ws  = (u16*)(ws + 33554432u);   // 8MB  [B,H,hd,S] bf16
  u16* ctx    = (u16*)(ws + 41943040u);   // 8MB  [4096][1024] bf16
  u16* biasb  = hsb;                      // bias bf16 overlays hsb after gemm<0>

  cvt_f32_bf16<<<4096, 256, 0, stream>>>(hs, hsb, 1048576);
  transpose_w_bf16<<<dim3(96, 32), 256, 0, stream>>>(c_attn_w, wqkvT, 1024, 3072);
  transpose_w_bf16<<<dim3(32, 32), 256, 0, stream>>>(c_proj_w, wprojT, 1024, 1024);

  gemm_bt<0><<<dim3(24, 32), 256, 0, stream>>>(hsb, wqkvT, c_attn_b, out,
                                               q_ws, k_ws, vT_ws, 4096, 3072, 1024);

  // hsb is dead now; convert bias into its space
  cvt_f32_bf16<<<4096, 256, 0, stream>>>(attn_bias, biasb, 1048576);

  attn_fused<<<dim3(1024), 256, 0, stream>>>(q_ws, k_ws, vT_ws, biasb, ctx);

  gemm_bt<1><<<dim3(8, 32), 256, 0, stream>>>(ctx, wprojT, c_proj_b, out,
                                              (u16*)nullptr, (u16*)nullptr, (u16*)nullptr,
                                              4096, 1024, 1024);
}

// Round 4
// 159.294 us; speedup vs baseline: 2.1149x; 1.1259x over previous
//
#include <hip/hip_runtime.h>
#include <hip/hip_bf16.h>
#include <stdint.h>

// GPT-2 prefill attention: B=2, S=2048, D=1024, H=16, hd=64.
// cvt/transpose prepass -> QKV GEMM (bf16 MFMA) -> bias tiling -> flash attn -> proj GEMM.

typedef __attribute__((ext_vector_type(4))) float f32x4;
typedef __attribute__((ext_vector_type(8))) short s16x8;
typedef __attribute__((ext_vector_type(4))) short s16x4;
typedef unsigned short u16;

#define LOG2E 1.4426950408889634f
#define QSCALE 0.18033688011112042f  // 0.125 * LOG2E

__device__ __forceinline__ u16 f2bf(float f) {
  unsigned w;
  asm("v_cvt_pk_bf16_f32 %0, %1, %2" : "=v"(w) : "v"(f), "v"(f));
  return (u16)w;
}
__device__ __forceinline__ float bf2f(u16 h) {
  unsigned int x = ((unsigned int)h) << 16;
  return __builtin_bit_cast(float, x);
}

__device__ __forceinline__ void gload_lds16(const u16* g, u16* lds) {
  __builtin_amdgcn_global_load_lds(
      (const __attribute__((address_space(1))) unsigned int*)g,
      (__attribute__((address_space(3))) unsigned int*)lds, 16, 0, 0);
}

// ---------------- prepass kernels ----------------

__global__ __launch_bounds__(256) void cvt_f32_bf16(const float* __restrict__ x,
                                                    u16* __restrict__ y, int n4) {
  int i = blockIdx.x * 256 + threadIdx.x;
  if (i < n4) {
    f32x4 v = *(const f32x4*)&x[(size_t)i * 4];
    s16x4 o;
    o[0] = (short)f2bf(v[0]); o[1] = (short)f2bf(v[1]);
    o[2] = (short)f2bf(v[2]); o[3] = (short)f2bf(v[3]);
    *(s16x4*)&y[(size_t)i * 4] = o;
  }
}

// W[K][N] f32 -> WT[N][K] bf16
__global__ __launch_bounds__(256) void transpose_w_bf16(const float* __restrict__ W,
                                                        u16* __restrict__ WT,
                                                        int K, int N) {
  __shared__ float tile[32][33];
  const int n0 = blockIdx.x * 32, k0 = blockIdx.y * 32;
  const int tx = threadIdx.x & 31, ty = threadIdx.x >> 5;
#pragma unroll
  for (int i = 0; i < 32; i += 8)
    tile[ty + i][tx] = W[(size_t)(k0 + ty + i) * N + (n0 + tx)];
  __syncthreads();
#pragma unroll
  for (int i = 0; i < 32; i += 8)
    WT[(size_t)(n0 + ty + i) * K + (k0 + tx)] = f2bf(tile[tx][ty + i]);
}

// bias -> tiled bf16 table, *LOG2E, causal mask folded as -inf.
// T[((Q16*32 + K64)*64 + lane)*16 + nf*4 + u] for q=Q16*16+hi*4+u, k=K64*64+nf*16+c
__global__ __launch_bounds__(256) void bias_tile(const float* __restrict__ B,
                                                 u16* __restrict__ T) {
  const int t = blockIdx.x * 256 + threadIdx.x;   // 262144 total
  const int lane = t & 63, K64 = (t >> 6) & 31, Q16 = t >> 11;
  if (K64 > (Q16 >> 2)) return;                   // tiles never read by attn
  const int c = lane & 15, hi = lane >> 4;
  u16 v[16];
#pragma unroll
  for (int nf = 0; nf < 4; nf++)
#pragma unroll
    for (int u = 0; u < 4; u++) {
      const int q = Q16 * 16 + hi * 4 + u;
      const int k = K64 * 64 + nf * 16 + c;
      v[nf * 4 + u] = (k <= q) ? f2bf(B[(size_t)q * 2048 + k] * LOG2E) : (u16)0xFF80;
    }
  *(s16x8*)&T[(size_t)t * 16] = *(s16x8*)&v[0];
  *(s16x8*)&T[(size_t)t * 16 + 8] = *(s16x8*)&v[8];
}

// ---------------- GEMM: C[M][N] = A[M][K] * BT[N][K]^T + bias ----------------
// XCD-aware bijective swizzle on the flat block id (nwg % 8 == 0 at both launches).

template <int MODE>
__global__ __launch_bounds__(256) void gemm_bt(
    const u16* __restrict__ A, const u16* __restrict__ BT,
    const float* __restrict__ bias, float* __restrict__ outF,
    u16* __restrict__ q_ws, u16* __restrict__ k_ws, u16* __restrict__ vT_ws,
    int M, int N, int K) {
  __shared__ u16 As[128 * 32];
  __shared__ u16 Bs[128 * 32];
  const int nwg = gridDim.x * gridDim.y;
  int flat = blockIdx.y * gridDim.x + blockIdx.x;
  flat = (flat & 7) * (nwg >> 3) + (flat >> 3);
  const int m0 = (flat / gridDim.x) * 128, n0 = (flat % gridDim.x) * 128;
  const int tid = threadIdx.x;
  const int wid = tid >> 6, lane = tid & 63;
  const int c = lane & 15, hi = lane >> 4;
  const int wm = wid >> 1, wn = wid & 1;
  const int srow = lane >> 2;
  const int skp = (lane & 3) * 8;

  f32x4 acc[4][4] = {};

  for (int k0 = 0; k0 < K; k0 += 32) {
#pragma unroll
    for (int t = 0; t < 2; t++) {
      const int rowl = wid * 32 + t * 16;
      gload_lds16(&A[(size_t)(m0 + rowl + srow) * K + k0 + skp], &As[rowl * 32]);
      gload_lds16(&BT[(size_t)(n0 + rowl + srow) * K + k0 + skp], &Bs[rowl * 32]);
    }
    __syncthreads();
    s16x8 af[4], bfr[4];
#pragma unroll
    for (int i = 0; i < 4; i++)
      af[i] = *(const s16x8*)&As[(wm * 64 + i * 16 + c) * 32 + hi * 8];
#pragma unroll
    for (int i = 0; i < 4; i++)
      bfr[i] = *(const s16x8*)&Bs[(wn * 64 + i * 16 + c) * 32 + hi * 8];
#pragma unroll
    for (int i = 0; i < 4; i++)
#pragma unroll
      for (int j = 0; j < 4; j++)
        acc[i][j] = __builtin_amdgcn_mfma_f32_16x16x32_bf16(af[i], bfr[j], acc[i][j], 0, 0, 0);
    __syncthreads();
  }

#pragma unroll
  for (int i = 0; i < 4; i++) {
#pragma unroll
    for (int j = 0; j < 4; j++) {
      const int col = n0 + wn * 64 + j * 16 + c;
      const int rb = m0 + wm * 64 + i * 16 + hi * 4;
      const float bv = bias[col];
      if (MODE == 1) {
#pragma unroll
        for (int u = 0; u < 4; u++)
          outF[(size_t)(rb + u) * N + col] = acc[i][j][u] + bv;
      } else {
        const int which = col >> 10;          // 0=q 1=k 2=v
        const int h = (col >> 6) & 15, d = col & 63;
#pragma unroll
        for (int u = 0; u < 4; u++) {
          const int r = rb + u;
          const int b = r >> 11, s = r & 2047;
          const size_t idx = (size_t)(b * 16 + h) * 131072u + (size_t)s * 64 + d;
          const float v = acc[i][j][u] + bv;
          if (which == 0) {
            q_ws[idx] = f2bf(v * QSCALE);     // fold 1/sqrt(hd) * LOG2E
          } else if (which == 1) {
            outF[4194304u + idx] = v;
            k_ws[idx] = f2bf(v);
          } else {
            outF[8388608u + idx] = v;
            vT_ws[(size_t)(b * 16 + h) * 131072u + (size_t)d * 2048 + s] = f2bf(v);
          }
        }
      }
    }
  }
}

// ---------------- fused causal attention ----------------
// 1024 blocks, 4 waves; balanced (bh,qblk) remap; K/V double-buffered in LDS
// (XOR-swizzled via pre-swizzled global src); P via swizzled LDS (round-2 proven).
// New: tiled bias table (mask+LOG2E folded), exp2 domain, deferred rescale,
// lane-partial l-sum, 1-op f2bf.

__global__ __launch_bounds__(256, 4) void attn_fused(
    const u16* __restrict__ q_ws, const u16* __restrict__ k_ws,
    const u16* __restrict__ vT_ws, const u16* __restrict__ biasT,
    u16* __restrict__ ctx) {
  __shared__ u16 Ks[2][64 * 64];
  __shared__ u16 Vs[2][64 * 64];
  __shared__ u16 P_lds[4 * 16 * 64];

  const int id = blockIdx.x;
  const int bh = (id & 7) * 4 + ((id >> 3) & 3);
  const int j = id >> 5, j0 = j & 7, sg = j >> 3;
  const int qblk = (sg == 0) ? j0 : (sg == 1) ? (15 - j0)
                 : (sg == 2) ? (16 + j0) : (31 - j0);

  const int wid = threadIdx.x >> 6, lane = threadIdx.x & 63;
  const int c = lane & 15, hi = lane >> 4;
  const int qrow0 = qblk * 64 + wid * 16;

  const u16* qh = q_ws + (size_t)bh * 131072u;
  const u16* kh = k_ws + (size_t)bh * 131072u;
  const u16* vh = vT_ws + (size_t)bh * 131072u;

  const s16x8 qf0 = *(const s16x8*)&qh[(size_t)(qrow0 + c) * 64 + hi * 8];
  const s16x8 qf1 = *(const s16x8*)&qh[(size_t)(qrow0 + c) * 64 + 32 + hi * 8];

  const int sl_r = lane >> 3, sl_c = lane & 7;

  f32x4 o[4] = {};
  float mrow[4] = {-1e30f, -1e30f, -1e30f, -1e30f};
  float lpart[4] = {0.f, 0.f, 0.f, 0.f};
  u16* pw = &P_lds[wid * 1024];

#define STAGE(BUF, N0)                                                        \
  {                                                                           \
    _Pragma("unroll")                                                         \
    for (int t = 0; t < 2; t++) {                                             \
      const int rb = wid * 16 + t * 8;                                        \
      const int r = rb + sl_r;                                                \
      gload_lds16(&kh[(size_t)((N0) + r) * 64 + ((sl_c ^ (r & 7)) * 8)],      \
                  &Ks[BUF][rb * 64]);                                         \
      gload_lds16(&vh[(size_t)r * 2048 + (N0) + ((sl_c ^ (r & 7)) * 8)],      \
                  &Vs[BUF][rb * 64]);                                         \
    }                                                                         \
  }

  STAGE(0, 0);
  __syncthreads();

  int buf = 0;
  const int sw0 = (hi ^ (c & 7)) * 8;
  const int sw1 = ((4 + hi) ^ (c & 7)) * 8;
  const int nkt = qblk + 1;
  const int Q16w = qblk * 4 + wid;

  for (int kt = 0; kt < nkt; ++kt) {
    const int n0 = kt * 64;

    // bias tile (issued before staging so its wait leaves staging in flight)
    const size_t bb = ((size_t)(Q16w * 32 + kt) * 64 + lane) * 16;
    const s16x8 b0 = *(const s16x8*)&biasT[bb];
    const s16x8 b1 = *(const s16x8*)&biasT[bb + 8];

    if (kt + 1 < nkt) {
      if (buf) { STAGE(0, n0 + 64); } else { STAGE(1, n0 + 64); }
    }

    // QK^T from LDS
    f32x4 sfr[4];
#pragma unroll
    for (int nf = 0; nf < 4; nf++) {
      const int row = nf * 16 + c;
      const s16x8 kf0 = *(const s16x8*)&Ks[buf][row * 64 + sw0];
      const s16x8 kf1 = *(const s16x8*)&Ks[buf][row * 64 + sw1];
      f32x4 a = {};
      a = __builtin_amdgcn_mfma_f32_16x16x32_bf16(qf0, kf0, a, 0, 0, 0);
      a = __builtin_amdgcn_mfma_f32_16x16x32_bf16(qf1, kf1, a, 0, 0, 0);
      sfr[nf] = a;
    }

    // add bias (log2 domain; mask folded as -inf)
#pragma unroll
    for (int nf = 0; nf < 4; nf++)
#pragma unroll
      for (int u = 0; u < 4; u++) {
        const int i = nf * 4 + u;
        sfr[nf][u] += bf2f((u16)(i < 8 ? b0[i] : b1[i - 8]));
      }

    // per-row tile max
    float tmax[4];
#pragma unroll
    for (int u = 0; u < 4; u++) {
      float t = fmaxf(fmaxf(sfr[0][u], sfr[1][u]), fmaxf(sfr[2][u], sfr[3][u]));
      t = fmaxf(t, __shfl_xor(t, 1));
      t = fmaxf(t, __shfl_xor(t, 2));
      t = fmaxf(t, __shfl_xor(t, 4));
      t = fmaxf(t, __shfl_xor(t, 8));
      tmax[u] = t;
    }
    // deferred rescale: only when max grows by > 8 (log2 units)
    const bool grow = (tmax[0] > mrow[0] + 8.f) | (tmax[1] > mrow[1] + 8.f) |
                      (tmax[2] > mrow[2] + 8.f) | (tmax[3] > mrow[3] + 8.f);
    if (__any(grow)) {
#pragma unroll
      for (int u = 0; u < 4; u++) {
        const float nm = fmaxf(mrow[u], tmax[u]);
        const float al = exp2f(mrow[u] - nm);
        mrow[u] = nm;
        lpart[u] *= al;
        o[0][u] *= al; o[1][u] *= al; o[2][u] *= al; o[3][u] *= al;
      }
    }

    // exp2 + lane-partial row-sum (cross-lane reduce deferred to end)
#pragma unroll
    for (int u = 0; u < 4; u++) {
      const float p0 = exp2f(sfr[0][u] - mrow[u]);
      const float p1 = exp2f(sfr[1][u] - mrow[u]);
      const float p2 = exp2f(sfr[2][u] - mrow[u]);
      const float p3 = exp2f(sfr[3][u] - mrow[u]);
      sfr[0][u] = p0; sfr[1][u] = p1; sfr[2][u] = p2; sfr[3][u] = p3;
      lpart[u] += (p0 + p1) + (p2 + p3);
    }

    // P (D-layout) -> LDS, XOR-swizzled (round-2 proven layout)
#pragma unroll
    for (int nf = 0; nf < 4; nf++) {
      const int colb = nf * 16 + c;
      const int slot = colb >> 3;
#pragma unroll
      for (int u = 0; u < 4; u++) {
        const int r = hi * 4 + u;
        pw[r * 64 + (((slot ^ (r & 7)) << 3) | (colb & 7))] = f2bf(sfr[nf][u]);
      }
    }

    // PV: P from LDS (A-frag), V from LDS (swizzled)
#pragma unroll
    for (int ks = 0; ks < 2; ks++) {
      const int rslot = ks * 4 + hi;
      const s16x8 pf = *(const s16x8*)&pw[c * 64 + ((rslot ^ (c & 7)) << 3)];
      const int sw = ks ? sw1 : sw0;
#pragma unroll
      for (int d0 = 0; d0 < 4; d0++) {
        const s16x8 vf = *(const s16x8*)&Vs[buf][(d0 * 16 + c) * 64 + sw];
        o[d0] = __builtin_amdgcn_mfma_f32_16x16x32_bf16(pf, vf, o[d0], 0, 0, 0);
      }
    }

    __syncthreads();
    buf ^= 1;
  }
#undef STAGE

  // deferred cross-lane l reduction
#pragma unroll
  for (int u = 0; u < 4; u++) {
    float t = lpart[u];
    t += __shfl_xor(t, 1);
    t += __shfl_xor(t, 2);
    t += __shfl_xor(t, 4);
    t += __shfl_xor(t, 8);
    lpart[u] = t;
  }

  const int b = bh >> 4, h = bh & 15;
#pragma unroll
  for (int u = 0; u < 4; u++) {
    const float inv = 1.0f / lpart[u];
    const int tok = b * 2048 + qrow0 + hi * 4 + u;
#pragma unroll
    for (int d0 = 0; d0 < 4; d0++)
      ctx[(size_t)tok * 1024 + h * 64 + d0 * 16 + c] = f2bf(o[d0][u] * inv);
  }
}

// ---------------- launch ----------------

extern "C" void kernel_launch(void* const* d_in, const int* in_sizes, int n_in,
                              void* d_out, int out_size, void* d_ws, size_t ws_size,
                              hipStream_t stream) {
  const float* hs        = (const float*)d_in[0];  // [2,2048,1024]
  const float* c_attn_w  = (const float*)d_in[1];  // [1024,3072]
  const float* c_attn_b  = (const float*)d_in[2];  // [3072]
  const float* attn_bias = (const float*)d_in[3];  // [2048,2048]
  const float* c_proj_w  = (const float*)d_in[4];  // [1024,1024]
  const float* c_proj_b  = (const float*)d_in[5];  // [1024]
  float* out = (float*)d_out;  // out(4M) | k(4M) | v(4M)

  uint8_t* ws = (uint8_t*)d_ws;
  u16* hsb    = (u16*)(ws + 0);           // 8MB [4096][1024] bf16 (reused for biasT)
  u16* wqkvT  = (u16*)(ws + 8388608u);    // 6MB [3072][1024] bf16
  u16* wprojT = (u16*)(ws + 14680064u);   // 2MB [1024][1024] bf16
  u16* q_ws   = (u16*)(ws + 16777216u);   // 8MB [B,H,S,hd] bf16 (q * QSCALE)
  u16* k_ws   = (u16*)(ws + 25165824u);   // 8MB [B,H,S,hd] bf16
  u16* vT_ws  = (u16*)(ws + 33554432u);   // 8MB [B,H,hd,S] bf16
  u16* ctx    = (u16*)(ws + 41943040u);   // 8MB [4096][1024] bf16
  u16* biasT  = hsb;                      // overlays hsb after gemm<0>

  cvt_f32_bf16<<<4096, 256, 0, stream>>>(hs, hsb, 1048576);
  transpose_w_bf16<<<dim3(96, 32), 256, 0, stream>>>(c_attn_w, wqkvT, 1024, 3072);
  transpose_w_bf16<<<dim3(32, 32), 256, 0, stream>>>(c_proj_w, wprojT, 1024, 1024);

  gemm_bt<0><<<dim3(24, 32), 256, 0, stream>>>(hsb, wqkvT, c_attn_b, out,
                                               q_ws, k_ws, vT_ws, 4096, 3072, 1024);

  bias_tile<<<1024, 256, 0, stream>>>(attn_bias, biasT);

  attn_fused<<<dim3(1024), 256, 0, stream>>>(q_ws, k_ws, vT_ws, biasT, ctx);

  gemm_bt<1><<<dim3(8, 32), 256, 0, stream>>>(ctx, wprojT, c_proj_b, out,
                                              (u16*)nullptr, (u16*)nullptr, (u16*)nullptr,
                                              4096, 1024, 1024);
}

// Round 5
// 154.999 us; speedup vs baseline: 2.1735x; 1.0277x over previous
//
#include <hip/hip_runtime.h>
#include <hip/hip_bf16.h>
#include <stdint.h>

// GPT-2 prefill attention: B=2, S=2048, D=1024, H=16, hd=64.
// cvt/transpose prepass -> QKV GEMM (bf16 MFMA) -> bias tiling -> flash attn -> proj GEMM.
// attn: 32x32 swapped-QK^T, in-register softmax (cvt_pk + permlane32_swap), split-kv wave pairs.

typedef __attribute__((ext_vector_type(4))) float f32x4;
typedef __attribute__((ext_vector_type(16))) float f32x16;
typedef __attribute__((ext_vector_type(8))) short s16x8;
typedef __attribute__((ext_vector_type(4))) short s16x4;
typedef unsigned short u16;

#define LOG2E 1.4426950408889634f
#define QSCALE 0.18033688011112042f  // 0.125 * LOG2E

__device__ __forceinline__ u16 f2bf(float f) {
  unsigned w;
  asm("v_cvt_pk_bf16_f32 %0, %1, %2" : "=v"(w) : "v"(f), "v"(f));
  return (u16)w;
}
__device__ __forceinline__ unsigned cvtpk(float lo, float hi) {
  unsigned w;
  asm("v_cvt_pk_bf16_f32 %0, %1, %2" : "=v"(w) : "v"(lo), "v"(hi));
  return w;
}
__device__ __forceinline__ float bf2f(u16 h) {
  unsigned int x = ((unsigned int)h) << 16;
  return __builtin_bit_cast(float, x);
}
__device__ __forceinline__ float fexp2(float x) {   // raw v_exp_f32 (we live in log2 domain)
  float r;
  asm("v_exp_f32 %0, %1" : "=v"(r) : "v"(x));
  return r;
}
__device__ __forceinline__ void pl32swap(unsigned& a, unsigned& b) {
  asm volatile("v_permlane32_swap_b32 %0, %1" : "+v"(a), "+v"(b));
}
__device__ __forceinline__ s16x8 frag8(unsigned a, unsigned b, unsigned c, unsigned d) {
  union { unsigned u[4]; s16x8 v; } t;
  t.u[0] = a; t.u[1] = b; t.u[2] = c; t.u[3] = d;
  return t.v;
}
__device__ __forceinline__ f32x16 mfma32(s16x8 a, s16x8 b, f32x16 c) {
  return __builtin_amdgcn_mfma_f32_32x32x16_bf16(a, b, c, 0, 0, 0);
}

__device__ __forceinline__ void gload_lds16(const u16* g, u16* lds) {
  __builtin_amdgcn_global_load_lds(
      (const __attribute__((address_space(1))) unsigned int*)g,
      (__attribute__((address_space(3))) unsigned int*)lds, 16, 0, 0);
}

// ---------------- prepass kernels ----------------

__global__ __launch_bounds__(256) void cvt_f32_bf16(const float* __restrict__ x,
                                                    u16* __restrict__ y, int n4) {
  int i = blockIdx.x * 256 + threadIdx.x;
  if (i < n4) {
    f32x4 v = *(const f32x4*)&x[(size_t)i * 4];
    s16x4 o;
    o[0] = (short)f2bf(v[0]); o[1] = (short)f2bf(v[1]);
    o[2] = (short)f2bf(v[2]); o[3] = (short)f2bf(v[3]);
    *(s16x4*)&y[(size_t)i * 4] = o;
  }
}

// W[K][N] f32 -> WT[N][K] bf16
__global__ __launch_bounds__(256) void transpose_w_bf16(const float* __restrict__ W,
                                                        u16* __restrict__ WT,
                                                        int K, int N) {
  __shared__ float tile[32][33];
  const int n0 = blockIdx.x * 32, k0 = blockIdx.y * 32;
  const int tx = threadIdx.x & 31, ty = threadIdx.x >> 5;
#pragma unroll
  for (int i = 0; i < 32; i += 8)
    tile[ty + i][tx] = W[(size_t)(k0 + ty + i) * N + (n0 + tx)];
  __syncthreads();
#pragma unroll
  for (int i = 0; i < 32; i += 8)
    WT[(size_t)(n0 + ty + i) * K + (k0 + tx)] = f2bf(tile[tx][ty + i]);
}

// bias -> packed triangular table in the 32x32 MFMA C/D register layout, *LOG2E,
// causal mask folded as -inf. Entry (q32,kt,t,lane,reg):
//   q = q32*32 + (lane&31), k = kt*64 + t*32 + (reg&3) + 8*(reg>>2) + 4*(lane>>5)
// Packed pair index boff(q32) = (h + (q32&1))*(h+1), h = q32>>1; kt <= h.
__global__ __launch_bounds__(128) void bias_tile(const float* __restrict__ B,
                                                 u16* __restrict__ T) {
  const int kt = blockIdx.x;      // 0..31
  const int q32 = blockIdx.y;     // 0..63
  if (kt > (q32 >> 1)) return;
  const int t = threadIdx.x >> 6, lane = threadIdx.x & 63;
  const int hh = q32 >> 1;
  const size_t boff = (size_t)(hh + (q32 & 1)) * (hh + 1);
  const int q = q32 * 32 + (lane & 31);
  const int kb = kt * 64 + t * 32 + 4 * (lane >> 5);
  u16 v[16];
#pragma unroll
  for (int r = 0; r < 16; r++) {
    const int k = kb + (r & 3) + 8 * (r >> 2);
    v[r] = (k <= q) ? f2bf(B[(size_t)q * 2048 + k] * LOG2E) : (u16)0xFF80;
  }
  u16* dst = T + (boff + kt) * 2048 + t * 1024 + (size_t)lane * 16;
  *(s16x8*)dst = *(s16x8*)&v[0];
  *(s16x8*)(dst + 8) = *(s16x8*)&v[8];
}

// ---------------- GEMM: C[M][N] = A[M][K] * BT[N][K]^T + bias ----------------

template <int MODE>
__global__ __launch_bounds__(256) void gemm_bt(
    const u16* __restrict__ A, const u16* __restrict__ BT,
    const float* __restrict__ bias, float* __restrict__ outF,
    u16* __restrict__ q_ws, u16* __restrict__ k_ws, u16* __restrict__ vT_ws,
    int M, int N, int K) {
  __shared__ u16 As[128 * 32];
  __shared__ u16 Bs[128 * 32];
  const int nwg = gridDim.x * gridDim.y;
  int flat = blockIdx.y * gridDim.x + blockIdx.x;
  flat = (flat & 7) * (nwg >> 3) + (flat >> 3);
  const int m0 = (flat / gridDim.x) * 128, n0 = (flat % gridDim.x) * 128;
  const int tid = threadIdx.x;
  const int wid = tid >> 6, lane = tid & 63;
  const int c = lane & 15, hi = lane >> 4;
  const int wm = wid >> 1, wn = wid & 1;
  const int srow = lane >> 2;
  const int skp = (lane & 3) * 8;

  f32x4 acc[4][4] = {};

  for (int k0 = 0; k0 < K; k0 += 32) {
#pragma unroll
    for (int t = 0; t < 2; t++) {
      const int rowl = wid * 32 + t * 16;
      gload_lds16(&A[(size_t)(m0 + rowl + srow) * K + k0 + skp], &As[rowl * 32]);
      gload_lds16(&BT[(size_t)(n0 + rowl + srow) * K + k0 + skp], &Bs[rowl * 32]);
    }
    __syncthreads();
    s16x8 af[4], bfr[4];
#pragma unroll
    for (int i = 0; i < 4; i++)
      af[i] = *(const s16x8*)&As[(wm * 64 + i * 16 + c) * 32 + hi * 8];
#pragma unroll
    for (int i = 0; i < 4; i++)
      bfr[i] = *(const s16x8*)&Bs[(wn * 64 + i * 16 + c) * 32 + hi * 8];
#pragma unroll
    for (int i = 0; i < 4; i++)
#pragma unroll
      for (int j = 0; j < 4; j++)
        acc[i][j] = __builtin_amdgcn_mfma_f32_16x16x32_bf16(af[i], bfr[j], acc[i][j], 0, 0, 0);
    __syncthreads();
  }

#pragma unroll
  for (int i = 0; i < 4; i++) {
#pragma unroll
    for (int j = 0; j < 4; j++) {
      const int col = n0 + wn * 64 + j * 16 + c;
      const int rb = m0 + wm * 64 + i * 16 + hi * 4;
      const float bv = bias[col];
      if (MODE == 1) {
#pragma unroll
        for (int u = 0; u < 4; u++)
          outF[(size_t)(rb + u) * N + col] = acc[i][j][u] + bv;
      } else {
        const int which = col >> 10;          // 0=q 1=k 2=v
        const int h = (col >> 6) & 15, d = col & 63;
#pragma unroll
        for (int u = 0; u < 4; u++) {
          const int r = rb + u;
          const int b = r >> 11, s = r & 2047;
          const size_t idx = (size_t)(b * 16 + h) * 131072u + (size_t)s * 64 + d;
          const float v = acc[i][j][u] + bv;
          if (which == 0) {
            q_ws[idx] = f2bf(v * QSCALE);     // fold 1/sqrt(hd) * LOG2E
          } else if (which == 1) {
            outF[4194304u + idx] = v;
            k_ws[idx] = f2bf(v);
          } else {
            outF[8388608u + idx] = v;
            vT_ws[(size_t)(b * 16 + h) * 131072u + (size_t)d * 2048 + s] = f2bf(v);
          }
        }
      }
    }
  }
}

// ---------------- fused causal attention ----------------
// 1024 blocks, 4 waves: wave = (pq = q-subtile of 32, par = kv-tile parity).
// Swapped QK^T (mfma(K,Q)) -> lane owns one q-row -> lane-local softmax;
// P -> PV A-frags in-register via cvt_pk + permlane32_swap; bias as MFMA C-init.
// K/V double-buffered in LDS (XOR-swizzled, round-2/4 proven staging).

__global__ __launch_bounds__(256, 4) void attn_fused(
    const u16* __restrict__ q_ws, const u16* __restrict__ k_ws,
    const u16* __restrict__ vT_ws, const u16* __restrict__ biasT,
    u16* __restrict__ ctx) {
  __shared__ u16 Ks[2][64 * 64];
  __shared__ u16 Vs[2][64 * 64];

  const int id = blockIdx.x;
  const int bh = (id & 7) * 4 + ((id >> 3) & 3);
  const int j = id >> 5, j0 = j & 7, sg = j >> 3;
  const int qblk = (sg == 0) ? j0 : (sg == 1) ? (15 - j0)
                 : (sg == 2) ? (16 + j0) : (31 - j0);

  const int wid = threadIdx.x >> 6, lane = threadIdx.x & 63;
  const int pq = wid >> 1, par = wid & 1;
  const int l31 = lane & 31, hi5 = lane >> 5;
  const int qrow0 = qblk * 64 + pq * 32;

  const u16* qh = q_ws + (size_t)bh * 131072u;
  const u16* kh = k_ws + (size_t)bh * 131072u;
  const u16* vh = vT_ws + (size_t)bh * 131072u;

  // Q B-frags (n = q = l31, k-dim = d): step s covers d in [s*16 + hi5*8, +8)
  s16x8 qf[4];
#pragma unroll
  for (int s = 0; s < 4; s++)
    qf[s] = *(const s16x8*)&qh[(size_t)(qrow0 + l31) * 64 + s * 16 + hi5 * 8];

  // packed-triangular bias base for q32 = qblk*2 + pq
  const int q32 = qblk * 2 + pq;
  const int hh = q32 >> 1;
  const size_t boff = (size_t)(hh + (q32 & 1)) * (hh + 1);
  const u16* bbase = biasT + boff * 2048 + (size_t)lane * 16;

  const int sl_r = lane >> 3, sl_c = lane & 7;

  f32x16 o0 = {}, o1 = {};
  float mrow = -1e30f, lpart = 0.f;

#define STAGE(BUF, N0)                                                        \
  {                                                                           \
    _Pragma("unroll")                                                         \
    for (int t = 0; t < 2; t++) {                                             \
      const int rb = wid * 16 + t * 8;                                        \
      const int r = rb + sl_r;                                                \
      gload_lds16(&kh[(size_t)((N0) + r) * 64 + ((sl_c ^ (r & 7)) * 8)],      \
                  &Ks[BUF][rb * 64]);                                         \
      gload_lds16(&vh[(size_t)r * 2048 + (N0) + ((sl_c ^ (r & 7)) * 8)],      \
                  &Vs[BUF][rb * 64]);                                         \
    }                                                                         \
  }

  STAGE(0, 0);
  __syncthreads();

  int buf = 0;
  const int nkt = qblk + 1;
  const int swz = l31 & 7;   // row&7 for both row and row+32

  for (int kt = 0; kt < nkt; ++kt) {
    if (kt + 1 < nkt) {
      if (buf) { STAGE(0, kt * 64 + 64); } else { STAGE(1, kt * 64 + 64); }
    }

    if ((kt & 1) == par) {
      // ---- bias as C-init (log2 domain, mask folded as -inf) ----
      const u16* bt = bbase + (size_t)kt * 2048;
      const s16x8 b00 = *(const s16x8*)(bt);
      const s16x8 b01 = *(const s16x8*)(bt + 8);
      const s16x8 b10 = *(const s16x8*)(bt + 1024);
      const s16x8 b11 = *(const s16x8*)(bt + 1032);
      f32x16 s0, s1;
#pragma unroll
      for (int r = 0; r < 8; r++) {
        s0[r] = bf2f((u16)b00[r]); s0[r + 8] = bf2f((u16)b01[r]);
        s1[r] = bf2f((u16)b10[r]); s1[r + 8] = bf2f((u16)b11[r]);
      }

      // ---- QK^T swapped: s[t] += K_tile(t)^T-frag x Q ----
      const u16* ksb = &Ks[buf][0];
#pragma unroll
      for (int s = 0; s < 4; s++) {
        const int ch = ((s * 2 + hi5) ^ swz) * 8;
        const s16x8 a0 = *(const s16x8*)&ksb[l31 * 64 + ch];
        const s16x8 a1 = *(const s16x8*)&ksb[(32 + l31) * 64 + ch];
        s0 = mfma32(a0, qf[s], s0);
        s1 = mfma32(a1, qf[s], s1);
      }

      // ---- lane-local softmax (q = l31; lanes l/l+32 hold disjoint k halves) ----
      float t0 = fmaxf(fmaxf(s0[0], s0[1]), fmaxf(s0[2], s0[3]));
      float t1 = fmaxf(fmaxf(s0[4], s0[5]), fmaxf(s0[6], s0[7]));
      float t2 = fmaxf(fmaxf(s0[8], s0[9]), fmaxf(s0[10], s0[11]));
      float t3 = fmaxf(fmaxf(s0[12], s0[13]), fmaxf(s0[14], s0[15]));
      float t4 = fmaxf(fmaxf(s1[0], s1[1]), fmaxf(s1[2], s1[3]));
      float t5 = fmaxf(fmaxf(s1[4], s1[5]), fmaxf(s1[6], s1[7]));
      float t6 = fmaxf(fmaxf(s1[8], s1[9]), fmaxf(s1[10], s1[11]));
      float t7 = fmaxf(fmaxf(s1[12], s1[13]), fmaxf(s1[14], s1[15]));
      float tm = fmaxf(fmaxf(fmaxf(t0, t1), fmaxf(t2, t3)),
                       fmaxf(fmaxf(t4, t5), fmaxf(t6, t7)));
      tm = fmaxf(tm, __shfl_xor(tm, 32));

      if (__any(tm > mrow + 8.f)) {            // deferred rescale (THR=8, log2 units)
        const float nm = fmaxf(mrow, tm);
        const float al = fexp2(mrow - nm);
        mrow = nm;
        lpart *= al;
#pragma unroll
        for (int r = 0; r < 16; r++) { o0[r] *= al; o1[r] *= al; }
      }

      // ---- exp2 (raw v_exp_f32) + lane-partial row sum ----
      float a0s = 0.f, a1s = 0.f, a2s = 0.f, a3s = 0.f;
#pragma unroll
      for (int r = 0; r < 4; r++) {
        s0[r]      = fexp2(s0[r] - mrow);      a0s += s0[r];
        s0[r + 4]  = fexp2(s0[r + 4] - mrow);  a1s += s0[r + 4];
        s0[r + 8]  = fexp2(s0[r + 8] - mrow);  a2s += s0[r + 8];
        s0[r + 12] = fexp2(s0[r + 12] - mrow); a3s += s0[r + 12];
        s1[r]      = fexp2(s1[r] - mrow);      a0s += s1[r];
        s1[r + 4]  = fexp2(s1[r + 4] - mrow);  a1s += s1[r + 4];
        s1[r + 8]  = fexp2(s1[r + 8] - mrow);  a2s += s1[r + 8];
        s1[r + 12] = fexp2(s1[r + 12] - mrow); a3s += s1[r + 12];
      }
      lpart += (a0s + a1s) + (a2s + a3s);

      // ---- P -> PV in-register (cvt_pk pairs + permlane32_swap) ----
      const u16* vsb = &Vs[buf][0];
#pragma unroll
      for (int t = 0; t < 2; t++) {
        const f32x16& st = t ? s1 : s0;
        unsigned wv0 = cvtpk(st[0], st[1]),   wv1 = cvtpk(st[2], st[3]);
        unsigned wv2 = cvtpk(st[4], st[5]),   wv3 = cvtpk(st[6], st[7]);
        unsigned wv4 = cvtpk(st[8], st[9]),   wv5 = cvtpk(st[10], st[11]);
        unsigned wv6 = cvtpk(st[12], st[13]), wv7 = cvtpk(st[14], st[15]);
        pl32swap(wv0, wv2);  // -> slice(2t)   words 0,2
        pl32swap(wv1, wv3);  // -> slice(2t)   words 1,3
        pl32swap(wv4, wv6);  // -> slice(2t+1) words 0,2
        pl32swap(wv5, wv7);  // -> slice(2t+1) words 1,3
#pragma unroll
        for (int hf = 0; hf < 2; hf++) {
          const int s = t * 2 + hf;
          const s16x8 pa = hf ? frag8(wv4, wv5, wv6, wv7) : frag8(wv0, wv1, wv2, wv3);
          const int ch = ((s * 2 + hi5) ^ swz) * 8;
          const s16x8 v0 = *(const s16x8*)&vsb[l31 * 64 + ch];
          const s16x8 v1 = *(const s16x8*)&vsb[(32 + l31) * 64 + ch];
          o0 = mfma32(pa, v0, o0);
          o1 = mfma32(pa, v1, o1);
        }
      }
    }

    __syncthreads();
    buf ^= 1;
  }
#undef STAGE

  // ---- combine lane halves, then wave-pair (split-kv) merge via LDS ----
  lpart += __shfl_xor(lpart, 32);

  float* shm_o = (float*)&Ks[0][0];    // [2][64][32] f32 = 16KB
  float* shm_ml = (float*)&Vs[0][0];   // [2][64][2] f32 + lbuf at +512
  __syncthreads();
  if (par == 1) {
    const int base = (pq * 64 + lane) * 32;
#pragma unroll
    for (int r = 0; r < 16; r++) {
      shm_o[base + r] = o0[r];
      shm_o[base + 16 + r] = o1[r];
    }
    shm_ml[(pq * 64 + lane) * 2 + 0] = mrow;
    shm_ml[(pq * 64 + lane) * 2 + 1] = lpart;
  }
  __syncthreads();
  if (par == 0) {
    const int base = (pq * 64 + lane) * 32;
    const float mb = shm_ml[(pq * 64 + lane) * 2 + 0];
    const float lb = shm_ml[(pq * 64 + lane) * 2 + 1];
    const float mm = fmaxf(mrow, mb);
    const float fa = fexp2(mrow - mm), fb = fexp2(mb - mm);
    const float lfull = lpart * fa + lb * fb;
#pragma unroll
    for (int r = 0; r < 16; r++) {
      o0[r] = o0[r] * fa + shm_o[base + r] * fb;
      o1[r] = o1[r] * fa + shm_o[base + 16 + r] * fb;
    }
    float* lbuf = shm_ml + 512 + pq * 32;
    if (lane < 32) lbuf[lane] = 1.0f / lfull;
    const int b = bh >> 4, h = bh & 15;
#pragma unroll
    for (int r = 0; r < 16; r++) {
      const int qloc = (r & 3) + 8 * (r >> 2) + 4 * hi5;
      const float linv = lbuf[qloc];
      const int tok = b * 2048 + qrow0 + qloc;
      ctx[(size_t)tok * 1024 + h * 64 + l31] = f2bf(o0[r] * linv);
      ctx[(size_t)tok * 1024 + h * 64 + 32 + l31] = f2bf(o1[r] * linv);
    }
  }
}

// ---------------- launch ----------------

extern "C" void kernel_launch(void* const* d_in, const int* in_sizes, int n_in,
                              void* d_out, int out_size, void* d_ws, size_t ws_size,
                              hipStream_t stream) {
  const float* hs        = (const float*)d_in[0];  // [2,2048,1024]
  const float* c_attn_w  = (const float*)d_in[1];  // [1024,3072]
  const float* c_attn_b  = (const float*)d_in[2];  // [3072]
  const float* attn_bias = (const float*)d_in[3];  // [2048,2048]
  const float* c_proj_w  = (const float*)d_in[4];  // [1024,1024]
  const float* c_proj_b  = (const float*)d_in[5];  // [1024]
  float* out = (float*)d_out;  // out(4M) | k(4M) | v(4M)

  uint8_t* ws = (uint8_t*)d_ws;
  u16* hsb    = (u16*)(ws + 0);           // 8MB [4096][1024] bf16 (reused for biasT, 4.3MB)
  u16* wqkvT  = (u16*)(ws + 8388608u);    // 6MB [3072][1024] bf16
  u16* wprojT = (u16*)(ws + 14680064u);   // 2MB [1024][1024] bf16
  u16* q_ws   = (u16*)(ws + 16777216u);   // 8MB [B,H,S,hd] bf16 (q * QSCALE)
  u16* k_ws   = (u16*)(ws + 25165824u);   // 8MB [B,H,S,hd] bf16
  u16* vT_ws  = (u16*)(ws + 33554432u);   // 8MB [B,H,hd,S] bf16
  u16* ctx    = (u16*)(ws + 41943040u);   // 8MB [4096][1024] bf16
  u16* biasT  = hsb;                      // overlays hsb after gemm<0>

  cvt_f32_bf16<<<4096, 256, 0, stream>>>(hs, hsb, 1048576);
  transpose_w_bf16<<<dim3(96, 32), 256, 0, stream>>>(c_attn_w, wqkvT, 1024, 3072);
  transpose_w_bf16<<<dim3(32, 32), 256, 0, stream>>>(c_proj_w, wprojT, 1024, 1024);

  gemm_bt<0><<<dim3(24, 32), 256, 0, stream>>>(hsb, wqkvT, c_attn_b, out,
                                               q_ws, k_ws, vT_ws, 4096, 3072, 1024);

  bias_tile<<<dim3(32, 64), 128, 0, stream>>>(attn_bias, biasT);

  attn_fused<<<dim3(1024), 256, 0, stream>>>(q_ws, k_ws, vT_ws, biasT, ctx);

  gemm_bt<1><<<dim3(8, 32), 256, 0, stream>>>(ctx, wprojT, c_proj_b, out,
                                              (u16*)nullptr, (u16*)nullptr, (u16*)nullptr,
                                              4096, 1024, 1024);
}

// Round 6
// 143.031 us; speedup vs baseline: 2.3554x; 1.0837x over previous
//
#include <hip/hip_runtime.h>
#include <hip/hip_bf16.h>
#include <stdint.h>

// GPT-2 prefill attention: B=2, S=2048, D=1024, H=16, hd=64.
// cvt/transpose prepass -> QKV GEMM (bf16 MFMA) -> bias tiling -> flash attn -> proj GEMM.
// attn: 32x32 swapped-QK^T, in-register softmax (cvt_pk + permlane32_swap),
// wave = (q-subtile, k-half) — both parities compute every kv tile; reg-q-space merge.

typedef __attribute__((ext_vector_type(4))) float f32x4;
typedef __attribute__((ext_vector_type(16))) float f32x16;
typedef __attribute__((ext_vector_type(8))) short s16x8;
typedef __attribute__((ext_vector_type(4))) short s16x4;
typedef unsigned short u16;

#define LOG2E 1.4426950408889634f
#define QSCALE 0.18033688011112042f  // 0.125 * LOG2E

__device__ __forceinline__ u16 f2bf(float f) {
  unsigned w;
  asm("v_cvt_pk_bf16_f32 %0, %1, %2" : "=v"(w) : "v"(f), "v"(f));
  return (u16)w;
}
__device__ __forceinline__ unsigned cvtpk(float lo, float hi) {
  unsigned w;
  asm("v_cvt_pk_bf16_f32 %0, %1, %2" : "=v"(w) : "v"(lo), "v"(hi));
  return w;
}
__device__ __forceinline__ float bf2f(u16 h) {
  unsigned int x = ((unsigned int)h) << 16;
  return __builtin_bit_cast(float, x);
}
__device__ __forceinline__ float fexp2(float x) {   // raw v_exp_f32 (log2 domain)
  float r;
  asm("v_exp_f32 %0, %1" : "=v"(r) : "v"(x));
  return r;
}
__device__ __forceinline__ void pl32swap(unsigned& a, unsigned& b) {
  asm volatile("v_permlane32_swap_b32 %0, %1" : "+v"(a), "+v"(b));
}
__device__ __forceinline__ s16x8 frag8(unsigned a, unsigned b, unsigned c, unsigned d) {
  union { unsigned u[4]; s16x8 v; } t;
  t.u[0] = a; t.u[1] = b; t.u[2] = c; t.u[3] = d;
  return t.v;
}
__device__ __forceinline__ f32x16 mfma32(s16x8 a, s16x8 b, f32x16 c) {
  return __builtin_amdgcn_mfma_f32_32x32x16_bf16(a, b, c, 0, 0, 0);
}

__device__ __forceinline__ void gload_lds16(const u16* g, u16* lds) {
  __builtin_amdgcn_global_load_lds(
      (const __attribute__((address_space(1))) unsigned int*)g,
      (__attribute__((address_space(3))) unsigned int*)lds, 16, 0, 0);
}

// ---------------- prepass kernels ----------------

__global__ __launch_bounds__(256) void cvt_f32_bf16(const float* __restrict__ x,
                                                    u16* __restrict__ y, int n4) {
  int i = blockIdx.x * 256 + threadIdx.x;
  if (i < n4) {
    f32x4 v = *(const f32x4*)&x[(size_t)i * 4];
    s16x4 o;
    o[0] = (short)f2bf(v[0]); o[1] = (short)f2bf(v[1]);
    o[2] = (short)f2bf(v[2]); o[3] = (short)f2bf(v[3]);
    *(s16x4*)&y[(size_t)i * 4] = o;
  }
}

// W[K][N] f32 -> WT[N][K] bf16
__global__ __launch_bounds__(256) void transpose_w_bf16(const float* __restrict__ W,
                                                        u16* __restrict__ WT,
                                                        int K, int N) {
  __shared__ float tile[32][33];
  const int n0 = blockIdx.x * 32, k0 = blockIdx.y * 32;
  const int tx = threadIdx.x & 31, ty = threadIdx.x >> 5;
#pragma unroll
  for (int i = 0; i < 32; i += 8)
    tile[ty + i][tx] = W[(size_t)(k0 + ty + i) * N + (n0 + tx)];
  __syncthreads();
#pragma unroll
  for (int i = 0; i < 32; i += 8)
    WT[(size_t)(n0 + ty + i) * K + (k0 + tx)] = f2bf(tile[tx][ty + i]);
}

// bias -> packed triangular table in the 32x32 MFMA C/D register layout, *LOG2E,
// causal mask folded as -inf. Entry (q32,kt,t,lane,reg):
//   q = q32*32 + (lane&31), k = kt*64 + t*32 + (reg&3) + 8*(reg>>2) + 4*(lane>>5)
// Packed pair index boff(q32) = (h + (q32&1))*(h+1), h = q32>>1; kt <= h.
__global__ __launch_bounds__(128) void bias_tile(const float* __restrict__ B,
                                                 u16* __restrict__ T) {
  const int kt = blockIdx.x;      // 0..31
  const int q32 = blockIdx.y;     // 0..63
  if (kt > (q32 >> 1)) return;
  const int t = threadIdx.x >> 6, lane = threadIdx.x & 63;
  const int hh = q32 >> 1;
  const size_t boff = (size_t)(hh + (q32 & 1)) * (hh + 1);
  const int q = q32 * 32 + (lane & 31);
  const int kb = kt * 64 + t * 32 + 4 * (lane >> 5);
  u16 v[16];
#pragma unroll
  for (int r = 0; r < 16; r++) {
    const int k = kb + (r & 3) + 8 * (r >> 2);
    v[r] = (k <= q) ? f2bf(B[(size_t)q * 2048 + k] * LOG2E) : (u16)0xFF80;
  }
  u16* dst = T + (boff + kt) * 2048 + t * 1024 + (size_t)lane * 16;
  *(s16x8*)dst = *(s16x8*)&v[0];
  *(s16x8*)(dst + 8) = *(s16x8*)&v[8];
}

// ---------------- GEMM: C[M][N] = A[M][K] * BT[N][K]^T + bias ----------------

template <int MODE>
__global__ __launch_bounds__(256) void gemm_bt(
    const u16* __restrict__ A, const u16* __restrict__ BT,
    const float* __restrict__ bias, float* __restrict__ outF,
    u16* __restrict__ q_ws, u16* __restrict__ k_ws, u16* __restrict__ vT_ws,
    int M, int N, int K) {
  __shared__ u16 As[128 * 32];
  __shared__ u16 Bs[128 * 32];
  const int nwg = gridDim.x * gridDim.y;
  int flat = blockIdx.y * gridDim.x + blockIdx.x;
  flat = (flat & 7) * (nwg >> 3) + (flat >> 3);
  const int m0 = (flat / gridDim.x) * 128, n0 = (flat % gridDim.x) * 128;
  const int tid = threadIdx.x;
  const int wid = tid >> 6, lane = tid & 63;
  const int c = lane & 15, hi = lane >> 4;
  const int wm = wid >> 1, wn = wid & 1;
  const int srow = lane >> 2;
  const int skp = (lane & 3) * 8;

  f32x4 acc[4][4] = {};

  for (int k0 = 0; k0 < K; k0 += 32) {
#pragma unroll
    for (int t = 0; t < 2; t++) {
      const int rowl = wid * 32 + t * 16;
      gload_lds16(&A[(size_t)(m0 + rowl + srow) * K + k0 + skp], &As[rowl * 32]);
      gload_lds16(&BT[(size_t)(n0 + rowl + srow) * K + k0 + skp], &Bs[rowl * 32]);
    }
    __syncthreads();
    s16x8 af[4], bfr[4];
#pragma unroll
    for (int i = 0; i < 4; i++)
      af[i] = *(const s16x8*)&As[(wm * 64 + i * 16 + c) * 32 + hi * 8];
#pragma unroll
    for (int i = 0; i < 4; i++)
      bfr[i] = *(const s16x8*)&Bs[(wn * 64 + i * 16 + c) * 32 + hi * 8];
#pragma unroll
    for (int i = 0; i < 4; i++)
#pragma unroll
      for (int j = 0; j < 4; j++)
        acc[i][j] = __builtin_amdgcn_mfma_f32_16x16x32_bf16(af[i], bfr[j], acc[i][j], 0, 0, 0);
    __syncthreads();
  }

#pragma unroll
  for (int i = 0; i < 4; i++) {
#pragma unroll
    for (int j = 0; j < 4; j++) {
      const int col = n0 + wn * 64 + j * 16 + c;
      const int rb = m0 + wm * 64 + i * 16 + hi * 4;
      const float bv = bias[col];
      if (MODE == 1) {
#pragma unroll
        for (int u = 0; u < 4; u++)
          outF[(size_t)(rb + u) * N + col] = acc[i][j][u] + bv;
      } else {
        const int which = col >> 10;          // 0=q 1=k 2=v
        const int h = (col >> 6) & 15, d = col & 63;
#pragma unroll
        for (int u = 0; u < 4; u++) {
          const int r = rb + u;
          const int b = r >> 11, s = r & 2047;
          const size_t idx = (size_t)(b * 16 + h) * 131072u + (size_t)s * 64 + d;
          const float v = acc[i][j][u] + bv;
          if (which == 0) {
            q_ws[idx] = f2bf(v * QSCALE);     // fold 1/sqrt(hd) * LOG2E
          } else if (which == 1) {
            outF[4194304u + idx] = v;
            k_ws[idx] = f2bf(v);
          } else {
            outF[8388608u + idx] = v;
            vT_ws[(size_t)(b * 16 + h) * 131072u + (size_t)d * 2048 + s] = f2bf(v);
          }
        }
      }
    }
  }
}

// ---------------- fused causal attention ----------------
// 1024 blocks, 4 waves: wave = (pq = q-subtile of 32, par = k-half of every tile).
// Swapped QK^T (mfma(K,Q)) -> lane owns one q-column -> lane-local softmax;
// P -> PV A-frags in-register via cvt_pk + permlane32_swap; bias as MFMA C-init
// (prefetched one tile ahead). End merge across k-halves done in reg-q space.

__global__ __launch_bounds__(256, 4) void attn_fused(
    const u16* __restrict__ q_ws, const u16* __restrict__ k_ws,
    const u16* __restrict__ vT_ws, const u16* __restrict__ biasT,
    u16* __restrict__ ctx) {
  __shared__ u16 Ks[2][64 * 64];
  __shared__ u16 Vs[2][64 * 64];

  const int id = blockIdx.x;
  const int bh = (id & 7) * 4 + ((id >> 3) & 3);
  const int j = id >> 5, j0 = j & 7, sg = j >> 3;
  const int qblk = (sg == 0) ? j0 : (sg == 1) ? (15 - j0)
                 : (sg == 2) ? (16 + j0) : (31 - j0);

  const int wid = threadIdx.x >> 6, lane = threadIdx.x & 63;
  const int pq = wid >> 1, par = wid & 1;
  const int l31 = lane & 31, hi5 = lane >> 5;
  const int qrow0 = qblk * 64 + pq * 32;

  const u16* qh = q_ws + (size_t)bh * 131072u;
  const u16* kh = k_ws + (size_t)bh * 131072u;
  const u16* vh = vT_ws + (size_t)bh * 131072u;

  // Q B-frags (n = q = l31, k-dim = d): step s covers d in [s*16 + hi5*8, +8)
  s16x8 qf[4];
#pragma unroll
  for (int s = 0; s < 4; s++)
    qf[s] = *(const s16x8*)&qh[(size_t)(qrow0 + l31) * 64 + s * 16 + hi5 * 8];

  // packed-triangular bias base for q32 = qblk*2 + pq; k-half selected by par
  const int q32 = qblk * 2 + pq;
  const int hh = q32 >> 1;     // == qblk
  const size_t boff = (size_t)(hh + (q32 & 1)) * (hh + 1);
  const u16* bbase = biasT + boff * 2048 + (size_t)par * 1024 + (size_t)lane * 16;

  const int sl_r = lane >> 3, sl_c = lane & 7;

  f32x16 o0 = {}, o1 = {};
  float mrow = -1e30f, lpart = 0.f;

#define STAGE(BUF, N0)                                                        \
  {                                                                           \
    _Pragma("unroll")                                                         \
    for (int t = 0; t < 2; t++) {                                             \
      const int rb = wid * 16 + t * 8;                                        \
      const int r = rb + sl_r;                                                \
      gload_lds16(&kh[(size_t)((N0) + r) * 64 + ((sl_c ^ (r & 7)) * 8)],      \
                  &Ks[BUF][rb * 64]);                                         \
      gload_lds16(&vh[(size_t)r * 2048 + (N0) + ((sl_c ^ (r & 7)) * 8)],      \
                  &Vs[BUF][rb * 64]);                                         \
    }                                                                         \
  }

  STAGE(0, 0);
  __syncthreads();

  int buf = 0;
  const int nkt = qblk + 1;
  const int swz = l31 & 7;
  const int arow = par * 32 + l31;

  // preload bias for kt = 0
  s16x8 bc0 = *(const s16x8*)(bbase);
  s16x8 bc1 = *(const s16x8*)(bbase + 8);

  for (int kt = 0; kt < nkt; ++kt) {
    if (kt + 1 < nkt) {
      if (buf) { STAGE(0, kt * 64 + 64); } else { STAGE(1, kt * 64 + 64); }
    }
    // prefetch next tile's bias (clamped; overlaps this tile's compute)
    const u16* btn = bbase + (size_t)((kt + 1 < nkt) ? kt + 1 : kt) * 2048;
    const s16x8 bn0 = *(const s16x8*)(btn);
    const s16x8 bn1 = *(const s16x8*)(btn + 8);

    // ---- bias as C-init (log2 domain, mask folded as -inf) ----
    f32x16 s0;
#pragma unroll
    for (int r = 0; r < 8; r++) {
      s0[r] = bf2f((u16)bc0[r]);
      s0[r + 8] = bf2f((u16)bc1[r]);
    }

    // ---- QK^T swapped (this wave's 32-k half): s0 += K-rows x Q ----
    const u16* ksb = &Ks[buf][0];
    __builtin_amdgcn_s_setprio(1);
#pragma unroll
    for (int s = 0; s < 4; s++) {
      const int ch = ((s * 2 + hi5) ^ swz) * 8;
      const s16x8 a0 = *(const s16x8*)&ksb[arow * 64 + ch];
      s0 = mfma32(a0, qf[s], s0);
    }
    __builtin_amdgcn_s_setprio(0);

    // ---- lane-local softmax (lane owns q-col l31; 16 k-values in regs) ----
    float t0 = fmaxf(fmaxf(s0[0], s0[1]), fmaxf(s0[2], s0[3]));
    float t1 = fmaxf(fmaxf(s0[4], s0[5]), fmaxf(s0[6], s0[7]));
    float t2 = fmaxf(fmaxf(s0[8], s0[9]), fmaxf(s0[10], s0[11]));
    float t3 = fmaxf(fmaxf(s0[12], s0[13]), fmaxf(s0[14], s0[15]));
    float tm = fmaxf(fmaxf(t0, t1), fmaxf(t2, t3));
    tm = fmaxf(tm, __shfl_xor(tm, 32));

    if (__any(tm > mrow + 8.f)) {            // deferred rescale (THR=8, log2 units)
      const float nm = fmaxf(mrow, tm);
      const float al = fexp2(mrow - nm);
      mrow = nm;
      lpart *= al;
#pragma unroll
      for (int r = 0; r < 16; r++) { o0[r] *= al; o1[r] *= al; }
    }

    // ---- exp2 + lane-partial row sum ----
    float a0s = 0.f, a1s = 0.f;
#pragma unroll
    for (int r = 0; r < 8; r++) {
      s0[r] = fexp2(s0[r] - mrow);       a0s += s0[r];
      s0[r + 8] = fexp2(s0[r + 8] - mrow); a1s += s0[r + 8];
    }
    lpart += a0s + a1s;

    // ---- P -> PV in-register (cvt_pk pairs + permlane32_swap) ----
    unsigned wv0 = cvtpk(s0[0], s0[1]),   wv1 = cvtpk(s0[2], s0[3]);
    unsigned wv2 = cvtpk(s0[4], s0[5]),   wv3 = cvtpk(s0[6], s0[7]);
    unsigned wv4 = cvtpk(s0[8], s0[9]),   wv5 = cvtpk(s0[10], s0[11]);
    unsigned wv6 = cvtpk(s0[12], s0[13]), wv7 = cvtpk(s0[14], s0[15]);
    pl32swap(wv0, wv2); pl32swap(wv1, wv3);
    pl32swap(wv4, wv6); pl32swap(wv5, wv7);

    const u16* vsb = &Vs[buf][0];
    __builtin_amdgcn_s_setprio(1);
#pragma unroll
    for (int hf = 0; hf < 2; hf++) {
      const s16x8 pa = hf ? frag8(wv4, wv5, wv6, wv7) : frag8(wv0, wv1, wv2, wv3);
      const int s = par * 2 + hf;
      const int ch = ((s * 2 + hi5) ^ swz) * 8;
      const s16x8 v0 = *(const s16x8*)&vsb[l31 * 64 + ch];
      const s16x8 v1 = *(const s16x8*)&vsb[(32 + l31) * 64 + ch];
      o0 = mfma32(pa, v0, o0);
      o1 = mfma32(pa, v1, o1);
    }
    __builtin_amdgcn_s_setprio(0);

    __syncthreads();
    buf ^= 1;
    bc0 = bn0; bc1 = bn1;
  }
#undef STAGE

  // combine hi5 halves (disjoint k-rows within this parity's half)
  lpart += __shfl_xor(lpart, 32);

  // ---- k-half merge, done per (q=reg, d=lane) — reg-q space ----
  float* obuf = (float*)&Ks[0][0];     // [32 reg][128 slot] f32 = 16KB
  float2* mlb = (float2*)&Vs[0][0];    // [(par*2+pq)*64 + q] -> (m, l), 2KB

  __syncthreads();
  if (hi5 == 0) mlb[(par * 2 + pq) * 64 + l31] = make_float2(mrow, lpart);
  if (par == 1) {
    const int slot = pq * 64 + lane;
#pragma unroll
    for (int r = 0; r < 16; r++) {
      obuf[r * 128 + slot] = o0[r];
      obuf[(16 + r) * 128 + slot] = o1[r];
    }
  }
  __syncthreads();
  if (par == 0) {
    const int slot = pq * 64 + lane;
    const int b = bh >> 4, h = bh & 15;
#pragma unroll
    for (int r = 0; r < 16; r++) {
      const int qloc = (r & 3) + 8 * (r >> 2) + 4 * hi5;
      const float2 Aml = mlb[pq * 64 + qloc];         // this parity (par=0)
      const float2 Bml = mlb[(2 + pq) * 64 + qloc];   // partner (par=1)
      const float mm = fmaxf(Aml.x, Bml.x);
      const float fa = fexp2(Aml.x - mm), fb = fexp2(Bml.x - mm);
      const float inv = __builtin_amdgcn_rcpf(Aml.y * fa + Bml.y * fb);
      const float om0 = (o0[r] * fa + obuf[r * 128 + slot] * fb) * inv;
      const float om1 = (o1[r] * fa + obuf[(16 + r) * 128 + slot] * fb) * inv;
      const int tok = b * 2048 + qrow0 + qloc;
      ctx[(size_t)tok * 1024 + h * 64 + l31] = f2bf(om0);
      ctx[(size_t)tok * 1024 + h * 64 + 32 + l31] = f2bf(om1);
    }
  }
}

// ---------------- launch ----------------

extern "C" void kernel_launch(void* const* d_in, const int* in_sizes, int n_in,
                              void* d_out, int out_size, void* d_ws, size_t ws_size,
                              hipStream_t stream) {
  const float* hs        = (const float*)d_in[0];  // [2,2048,1024]
  const float* c_attn_w  = (const float*)d_in[1];  // [1024,3072]
  const float* c_attn_b  = (const float*)d_in[2];  // [3072]
  const float* attn_bias = (const float*)d_in[3];  // [2048,2048]
  const float* c_proj_w  = (const float*)d_in[4];  // [1024,1024]
  const float* c_proj_b  = (const float*)d_in[5];  // [1024]
  float* out = (float*)d_out;  // out(4M) | k(4M) | v(4M)

  uint8_t* ws = (uint8_t*)d_ws;
  u16* hsb    = (u16*)(ws + 0);           // 8MB [4096][1024] bf16 (reused for biasT, 4.3MB)
  u16* wqkvT  = (u16*)(ws + 8388608u);    // 6MB [3072][1024] bf16
  u16* wprojT = (u16*)(ws + 14680064u);   // 2MB [1024][1024] bf16
  u16* q_ws   = (u16*)(ws + 16777216u);   // 8MB [B,H,S,hd] bf16 (q * QSCALE)
  u16* k_ws   = (u16*)(ws + 25165824u);   // 8MB [B,H,S,hd] bf16
  u16* vT_ws  = (u16*)(ws + 33554432u);   // 8MB [B,H,hd,S] bf16
  u16* ctx    = (u16*)(ws + 41943040u);   // 8MB [4096][1024] bf16
  u16* biasT  = hsb;                      // overlays hsb after gemm<0>

  cvt_f32_bf16<<<4096, 256, 0, stream>>>(hs, hsb, 1048576);
  transpose_w_bf16<<<dim3(96, 32), 256, 0, stream>>>(c_attn_w, wqkvT, 1024, 3072);
  transpose_w_bf16<<<dim3(32, 32), 256, 0, stream>>>(c_proj_w, wprojT, 1024, 1024);

  gemm_bt<0><<<dim3(24, 32), 256, 0, stream>>>(hsb, wqkvT, c_attn_b, out,
                                               q_ws, k_ws, vT_ws, 4096, 3072, 1024);

  bias_tile<<<dim3(32, 64), 128, 0, stream>>>(attn_bias, biasT);

  attn_fused<<<dim3(1024), 256, 0, stream>>>(q_ws, k_ws, vT_ws, biasT, ctx);

  gemm_bt<1><<<dim3(8, 32), 256, 0, stream>>>(ctx, wprojT, c_proj_b, out,
                                              (u16*)nullptr, (u16*)nullptr, (u16*)nullptr,
                                              4096, 1024, 1024);
}